// Round 1
// baseline (246.125 us; speedup 1.0000x reference)
//
#include <hip/hip_runtime.h>
#include <hip/hip_bf16.h>
#include <stdint.h>

// Problem constants: B=4, C=256, O=256, H=W=64, K=3, K2=9, KK=C*K2=2304
// ws layout: xT (NHWC bf16, 8,388,608 B) | Wp2 (MFMA-packed weights bf16,
//            1,179,648 B) | offs (fp32 conv output, 1,179,648 B)

typedef __bf16 bf16x8 __attribute__((ext_vector_type(8)));
typedef float  f32x4  __attribute__((ext_vector_type(4)));

__device__ __forceinline__ unsigned short f2bf(float f) {
    union { float f; unsigned u; } v; v.f = f;
    unsigned u = v.u;
    u += 0x7FFFu + ((u >> 16) & 1u);   // RNE
    return (unsigned short)(u >> 16);
}
__device__ __forceinline__ float bf2f(unsigned short s) {
    union { unsigned u; float f; } v; v.u = ((unsigned)s) << 16;
    return v.f;
}

// ---------------------------------------------------------------------------
// Kernel 1: x (B,C,H,W) fp32 -> xT (B,H,W,C) bf16.  One block = (b,h,cq):
// 64 channels x 64 w.  Read coalesced over w, LDS transpose, write coalesced
// over c (ushort4 = 8B/lane).
// ---------------------------------------------------------------------------
__global__ __launch_bounds__(256) void xpose_kernel(const float* __restrict__ x,
                                                    unsigned short* __restrict__ xT) {
    __shared__ unsigned short tile[64 * 72];   // [w][cl], pad 72 to break stride
    int blk = blockIdx.x;
    int cq = blk & 3;
    int bh = blk >> 2;                 // b*64 + h
    int t = threadIdx.x;
    int w = t & 63, row = t >> 6;
    const float* src = x + ((size_t)(bh >> 6) * 256 + cq * 64) * 4096 + (size_t)(bh & 63) * 64;
#pragma unroll
    for (int i = 0; i < 16; ++i) {
        int cl = i * 4 + row;
        float v = src[(size_t)cl * 4096 + w];
        tile[w * 72 + cl] = f2bf(v);
    }
    __syncthreads();
    unsigned short* dst = xT + (size_t)bh * 16384 + cq * 64;
#pragma unroll
    for (int i = 0; i < 4; ++i) {
        int item = i * 256 + t;
        int ww = item >> 4;
        int clq = item & 15;
        ushort4 v = *(const ushort4*)&tile[ww * 72 + clq * 4];
        *(ushort4*)&dst[ww * 256 + clq * 4] = v;
    }
}

// ---------------------------------------------------------------------------
// Kernel 2: deform_w (O,C,3,3) fp32 -> Wp2 bf16 in MFMA-B-fragment order.
// GEMM k = tap*256 + c.  For K-chunk kg (32 k's), quad q, lane-n:
//   Wp2[((kg*4+q)*256 + n)*8 + j]  holds  W[o=n][k = kg*32 + q*8 + j]
// so the GEMM's B-frag load is one lane-linear 16B read.
// ---------------------------------------------------------------------------
__global__ __launch_bounds__(256) void packw_kernel(const float* __restrict__ dw,
                                                    unsigned short* __restrict__ Wp2) {
    int idx = blockIdx.x * 256 + threadIdx.x;   // exactly 589824 threads
    int o = idx / 2304;
    int r = idx % 2304;
    int c = r / 9;
    int tap = r % 9;
    int k = tap * 256 + c;
    int chunk = k >> 5, quad = (k >> 3) & 3, j = k & 7;
    Wp2[(((chunk * 4 + quad) * 256) + o) * 8 + j] = f2bf(dw[idx]);
}

// ---------------------------------------------------------------------------
// Kernel 3: offsets = conv3x3(y, offset_w) + offset_b, fp32.
// One block per (b,h); thread = (w, cq); each thread sums 64 channels for all
// 18 outputs; LDS reduce over the 4 c-quarters.  Weights are wave-uniform
// (readfirstlane -> s_load); w+-1 neighbors via wave shuffles.
// ---------------------------------------------------------------------------
__global__ __launch_bounds__(256) void offs_kernel(const float* __restrict__ y,
                                                   const float* __restrict__ ow,
                                                   const float* __restrict__ ob,
                                                   float* __restrict__ offs) {
    __shared__ float red[4][18][64];
    int blk = blockIdx.x;
    int b = blk >> 6, h = blk & 63;
    int t = threadIdx.x;
    int w = t & 63, cq = t >> 6;
    float acc[18];
#pragma unroll
    for (int o = 0; o < 18; ++o) acc[o] = 0.f;
    const float* yb = y + (size_t)b * 256 * 4096;
    for (int i = 0; i < 64; ++i) {
        int c = cq * 64 + i;
        int cu = __builtin_amdgcn_readfirstlane(c);
        float v[3][3];
#pragma unroll
        for (int r = 0; r < 3; ++r) {
            int hr = h + r - 1;
            float ctr = 0.f;
            if (hr >= 0 && hr < 64) ctr = yb[((size_t)cu * 64 + hr) * 64 + w];
            float lf = __shfl_up(ctr, 1, 64);
            float rt = __shfl_down(ctr, 1, 64);
            v[r][0] = (w == 0) ? 0.f : lf;
            v[r][1] = ctr;
            v[r][2] = (w == 63) ? 0.f : rt;
        }
        const float* wp = ow + cu * 9;     // offset_w[o][c][tap] = ow[o*2304 + c*9 + tap]
#pragma unroll
        for (int o = 0; o < 18; ++o) {
            const float* wo = wp + o * 2304;
            float s = acc[o];
#pragma unroll
            for (int tap = 0; tap < 9; ++tap)
                s += wo[tap] * v[tap / 3][tap % 3];
            acc[o] = s;
        }
    }
#pragma unroll
    for (int o = 0; o < 18; ++o) red[cq][o][w] = acc[o];
    __syncthreads();
    for (int idx = t; idx < 18 * 64; idx += 256) {
        int o = idx >> 6, ww = idx & 63;
        float s = red[0][o][ww] + red[1][o][ww] + red[2][o][ww] + red[3][o][ww] + ob[o];
        offs[((size_t)b * 18 + o) * 4096 + h * 64 + ww] = s;
    }
}

// ---------------------------------------------------------------------------
// Kernel 4: implicit-GEMM deformable conv.
// Block = one (b,h) row: M=64 positions (m == w), N=256, K=2304.
// 512 threads = 8 waves; wave wv owns N-slice [wv*32, wv*32+32).
// Per tap: params (t<64) -> gather A chunk (64x256 bf16) to LDS -> 8 MFMA
// K-chunks (A: ds_read_b128, 2-way bank alias only; B: lane-linear 16B global
// loads from L2-resident Wp2).
// ---------------------------------------------------------------------------
__global__ __launch_bounds__(512, 2) void deform_kernel(
    const unsigned short* __restrict__ xT,
    const unsigned short* __restrict__ Wp2,
    const float* __restrict__ offs,
    const float* __restrict__ db,
    float* __restrict__ out)
{
    __shared__ unsigned short A_lds[64 * 264];   // [pos][c], +8 pad
    __shared__ float4 pw4[64];
    __shared__ int4   pi4[64];

    int blk = blockIdx.x;
    int b = blk >> 6, h = blk & 63;
    int t = threadIdx.x;
    int wv = t >> 6, lane = t & 63;
    int lq = lane >> 4, ln = lane & 15;

    const unsigned short* xtb = xT + (size_t)b * (64 * 64 * 256);

    f32x4 acc[4][2];
#pragma unroll
    for (int ms = 0; ms < 4; ++ms)
#pragma unroll
        for (int ns = 0; ns < 2; ++ns)
            acc[ms][ns] = (f32x4){0.f, 0.f, 0.f, 0.f};

    const float* offb = offs + (size_t)b * 18 * 4096 + h * 64;

    for (int tap = 0; tap < 9; ++tap) {
        __syncthreads();   // prev tap's MFMA done reading A_lds / gather done with params
        if (t < 64) {
            int ki = tap / 3, kj = tap % 3;
            float dy = offb[(tap * 2 + 0) * 4096 + t];
            float dx = offb[(tap * 2 + 1) * 4096 + t];
            float py = (float)(h - 1 + ki) + dy;
            float px = (float)(t - 1 + kj) + dx;
            float y0 = floorf(py), x0 = floorf(px);
            float wy1 = py - y0, wx1 = px - x0;
            float wy0 = 1.f - wy1, wx0 = 1.f - wx1;
            float y1 = y0 + 1.f, x1 = x0 + 1.f;
            float vy0 = (y0 >= 0.f && y0 <= 63.f) ? 1.f : 0.f;
            float vy1 = (y1 >= 0.f && y1 <= 63.f) ? 1.f : 0.f;
            float vx0 = (x0 >= 0.f && x0 <= 63.f) ? 1.f : 0.f;
            float vx1 = (x1 >= 0.f && x1 <= 63.f) ? 1.f : 0.f;
            int iy0 = (int)fminf(fmaxf(y0, 0.f), 63.f);
            int iy1 = (int)fminf(fmaxf(y1, 0.f), 63.f);
            int ix0 = (int)fminf(fmaxf(x0, 0.f), 63.f);
            int ix1 = (int)fminf(fmaxf(x1, 0.f), 63.f);
            pw4[t] = make_float4(wy0 * wx0 * vy0 * vx0,
                                 wy0 * wx1 * vy0 * vx1,
                                 wy1 * wx0 * vy1 * vx0,
                                 wy1 * wx1 * vy1 * vx1);
            pi4[t] = make_int4((iy0 * 64 + ix0) * 256,
                               (iy0 * 64 + ix1) * 256,
                               (iy1 * 64 + ix0) * 256,
                               (iy1 * 64 + ix1) * 256);
        }
        __syncthreads();
        // ---- gather: wave wv handles pos = i*8+wv, lanes cover 256 channels as 4-ch quads
        int c0 = lane * 4;
#pragma unroll
        for (int i = 0; i < 8; ++i) {
            int pos = i * 8 + wv;
            float4 wgt = pw4[pos];
            int4 o4 = pi4[pos];
            ushort4 a00 = *(const ushort4*)&xtb[o4.x + c0];
            ushort4 a01 = *(const ushort4*)&xtb[o4.y + c0];
            ushort4 a10 = *(const ushort4*)&xtb[o4.z + c0];
            ushort4 a11 = *(const ushort4*)&xtb[o4.w + c0];
            float r0 = wgt.x * bf2f(a00.x) + wgt.y * bf2f(a01.x) + wgt.z * bf2f(a10.x) + wgt.w * bf2f(a11.x);
            float r1 = wgt.x * bf2f(a00.y) + wgt.y * bf2f(a01.y) + wgt.z * bf2f(a10.y) + wgt.w * bf2f(a11.y);
            float r2 = wgt.x * bf2f(a00.z) + wgt.y * bf2f(a01.z) + wgt.z * bf2f(a10.z) + wgt.w * bf2f(a11.z);
            float r3 = wgt.x * bf2f(a00.w) + wgt.y * bf2f(a01.w) + wgt.z * bf2f(a10.w) + wgt.w * bf2f(a11.w);
            ushort4 res = make_ushort4(f2bf(r0), f2bf(r1), f2bf(r2), f2bf(r3));
            *(ushort4*)&A_lds[pos * 264 + c0] = res;
        }
        __syncthreads();
        // ---- MFMA over this tap's K=256 (8 chunks of 32)
#pragma unroll 2
        for (int kc = 0; kc < 8; ++kc) {
            bf16x8 af[4];
#pragma unroll
            for (int ms = 0; ms < 4; ++ms)
                af[ms] = *(const bf16x8*)&A_lds[(ms * 16 + ln) * 264 + kc * 32 + lq * 8];
            int kg = tap * 8 + kc;
            bf16x8 bfr[2];
#pragma unroll
            for (int ns = 0; ns < 2; ++ns) {
                int n = wv * 32 + ns * 16 + ln;
                bfr[ns] = *(const bf16x8*)&Wp2[(((kg * 4 + lq) * 256) + n) * 8];
            }
#pragma unroll
            for (int ms = 0; ms < 4; ++ms)
#pragma unroll
                for (int ns = 0; ns < 2; ++ns)
                    acc[ms][ns] = __builtin_amdgcn_mfma_f32_16x16x32_bf16(af[ms], bfr[ns], acc[ms][ns], 0, 0, 0);
        }
    }
    // ---- epilogue: D layout col=ln -> o, row=lq*4+r -> w
#pragma unroll
    for (int ns = 0; ns < 2; ++ns) {
        int o = wv * 32 + ns * 16 + ln;
        float bias = db[o];
        float* ob = out + (size_t)(b * 256 + o) * 4096 + h * 64;
#pragma unroll
        for (int ms = 0; ms < 4; ++ms) {
            int wb = ms * 16 + lq * 4;
            float4 st = make_float4(acc[ms][ns][0] + bias, acc[ms][ns][1] + bias,
                                    acc[ms][ns][2] + bias, acc[ms][ns][3] + bias);
            *(float4*)&ob[wb] = st;
        }
    }
}

extern "C" void kernel_launch(void* const* d_in, const int* in_sizes, int n_in,
                              void* d_out, int out_size, void* d_ws, size_t ws_size,
                              hipStream_t stream) {
    const float* x  = (const float*)d_in[0];
    const float* y  = (const float*)d_in[1];
    const float* ow = (const float*)d_in[2];
    const float* ob = (const float*)d_in[3];
    const float* dw = (const float*)d_in[4];
    const float* db = (const float*)d_in[5];
    float* out = (float*)d_out;

    unsigned short* xT  = (unsigned short*)d_ws;                               // 8,388,608 B
    unsigned short* Wp2 = (unsigned short*)((char*)d_ws + 8388608);            // 1,179,648 B
    float*          offs = (float*)((char*)d_ws + 8388608 + 1179648);          // 1,179,648 B

    hipLaunchKernelGGL(xpose_kernel, dim3(1024), dim3(256), 0, stream, x, xT);
    hipLaunchKernelGGL(packw_kernel, dim3(2304), dim3(256), 0, stream, dw, Wp2);
    hipLaunchKernelGGL(offs_kernel,  dim3(256),  dim3(256), 0, stream, y, ow, ob, offs);
    hipLaunchKernelGGL(deform_kernel, dim3(256), dim3(512), 0, stream, xT, Wp2, offs, db, out);
}

// Round 2
// 178.924 us; speedup vs baseline: 1.3756x; 1.3756x over previous
//
#include <hip/hip_runtime.h>
#include <hip/hip_bf16.h>
#include <stdint.h>

// Problem constants: B=4, C=256, O=256, H=W=64, K=3, K2=9, KK=C*K2=2304
// ws layout:
//   xT  (x NHWC bf16)            8,388,608 B  @ 0
//   yT  (y NHWC bf16)            8,388,608 B  @ 8 MiB
//   Wp2 (deform_w MFMA-packed)   1,179,648 B  @ 16 MiB
//   Bo  (offset_w MFMA-packed)     147,456 B  @ 16 MiB + 1,179,648
//   offs (fp32 conv out)         1,179,648 B  after Bo
// total ~18.6 MB

typedef __bf16 bf16x8 __attribute__((ext_vector_type(8)));
typedef float  f32x4  __attribute__((ext_vector_type(4)));

__device__ __forceinline__ unsigned short f2bf(float f) {
    union { float f; unsigned u; } v; v.f = f;
    unsigned u = v.u;
    u += 0x7FFFu + ((u >> 16) & 1u);   // RNE
    return (unsigned short)(u >> 16);
}
__device__ __forceinline__ float bf2f(unsigned short s) {
    union { unsigned u; float f; } v; v.u = ((unsigned)s) << 16;
    return v.f;
}

// ---------------------------------------------------------------------------
// Kernel 1: (B,C,H,W) fp32 -> (B,H,W,C) bf16 (used for both x and y).
// One block = (b,h,cq): 64 channels x 64 w.  Coalesced read over w, LDS
// transpose, coalesced write over c.
// ---------------------------------------------------------------------------
__global__ __launch_bounds__(256) void xpose_kernel(const float* __restrict__ x,
                                                    unsigned short* __restrict__ xT) {
    __shared__ unsigned short tile[64 * 72];   // [w][cl], pad 72 to break stride
    int blk = blockIdx.x;
    int cq = blk & 3;
    int bh = blk >> 2;                 // b*64 + h
    int t = threadIdx.x;
    int w = t & 63, row = t >> 6;
    const float* src = x + ((size_t)(bh >> 6) * 256 + cq * 64) * 4096 + (size_t)(bh & 63) * 64;
#pragma unroll
    for (int i = 0; i < 16; ++i) {
        int cl = i * 4 + row;
        float v = src[(size_t)cl * 4096 + w];
        tile[w * 72 + cl] = f2bf(v);
    }
    __syncthreads();
    unsigned short* dst = xT + (size_t)bh * 16384 + cq * 64;
#pragma unroll
    for (int i = 0; i < 4; ++i) {
        int item = i * 256 + t;
        int ww = item >> 4;
        int clq = item & 15;
        ushort4 v = *(const ushort4*)&tile[ww * 72 + clq * 4];
        *(ushort4*)&dst[ww * 256 + clq * 4] = v;
    }
}

// ---------------------------------------------------------------------------
// Kernel 2: deform_w (O,C,3,3) fp32 -> Wp2 bf16 in MFMA-B-fragment order.
// k = tap*256 + c.  Wp2[((kg*4+q)*256 + n)*8 + j] = W[o=n][k=kg*32+q*8+j]
// ---------------------------------------------------------------------------
__global__ __launch_bounds__(256) void packw_kernel(const float* __restrict__ dw,
                                                    unsigned short* __restrict__ Wp2) {
    int idx = blockIdx.x * 256 + threadIdx.x;   // exactly 589824 threads
    int o = idx / 2304;
    int r = idx % 2304;
    int c = r / 9;
    int tap = r % 9;
    int k = tap * 256 + c;
    int chunk = k >> 5, quad = (k >> 3) & 3, j = k & 7;
    Wp2[(((chunk * 4 + quad) * 256) + o) * 8 + j] = f2bf(dw[idx]);
}

// ---------------------------------------------------------------------------
// Kernel 2b: offset_w (18,C,3,3) fp32 -> Bo bf16, B-fragment order, N padded
// to 32 with zeros.  Bo[kg*1024 + lq*256 + n*8 + j] = ow[n][c][tap] where
// k = kg*32 + lq*8 + j, tap = k>>8, c = k&255.  73728 entries.
// ---------------------------------------------------------------------------
__global__ __launch_bounds__(256) void packow_kernel(const float* __restrict__ ow,
                                                     unsigned short* __restrict__ Bo) {
    int idx = blockIdx.x * 256 + threadIdx.x;   // 288 blocks
    int j = idx & 7;
    int n = (idx >> 3) & 31;
    int lq = (idx >> 8) & 3;
    int kg = idx >> 10;                // 0..71
    int k = kg * 32 + lq * 8 + j;
    int tap = k >> 8, c = k & 255;
    float v = (n < 18) ? ow[n * 2304 + c * 9 + tap] : 0.f;
    Bo[idx] = f2bf(v);
}

// ---------------------------------------------------------------------------
// Kernel 3: offsets conv via MFMA implicit GEMM.  Block = (b,h): M=64 (m=w),
// N=32 (18 valid), K=2304.  512 threads = 8 waves; wave = (ms = wv&3,
// ns = wv>>2); each wave: 1 MFMA per K-chunk, A and B direct 16B global loads
// (no LDS, no gather — im2col is just a shifted row of yT).
// ---------------------------------------------------------------------------
__global__ __launch_bounds__(512) void offs_mfma_kernel(
    const unsigned short* __restrict__ yT,
    const unsigned short* __restrict__ Bo,
    const float* __restrict__ ob,
    float* __restrict__ offs)
{
    int blk = blockIdx.x;
    int b = blk >> 6, h = blk & 63;
    int t = threadIdx.x;
    int wv = t >> 6, lane = t & 63;
    int ms = wv & 3, ns = wv >> 2;
    int lq = lane >> 4, ln = lane & 15;

    const unsigned short* ytb = yT + (size_t)b * (64 * 64 * 256);

    f32x4 acc = (f32x4){0.f, 0.f, 0.f, 0.f};

    for (int tap = 0; tap < 9; ++tap) {
        int ki = tap / 3, kj = tap % 3;
        int hr = h + ki - 1;
        int wr = ms * 16 + ln + kj - 1;
        bool valid = (hr >= 0) & (hr < 64) & (wr >= 0) & (wr < 64);
        const unsigned short* arow = ytb + ((size_t)(((hr & 63) * 64) + (wr & 63)) * 256);
#pragma unroll
        for (int kc = 0; kc < 8; ++kc) {
            bf16x8 af;
            if (valid) af = *(const bf16x8*)&arow[kc * 32 + lq * 8];
            else       af = (bf16x8)(__bf16)0.0f;
            bf16x8 bfr = *(const bf16x8*)&Bo[(tap * 8 + kc) * 1024 + lq * 256 + (ns * 16 + ln) * 8];
            acc = __builtin_amdgcn_mfma_f32_16x16x32_bf16(af, bfr, acc, 0, 0, 0);
        }
    }
    // D: col(n)=ln, row(m)=lq*4+r.  o = ns*16+ln (only o<18 stored), w = ms*16+lq*4+r
    int o = ns * 16 + ln;
    if (o < 18) {
        float bias = ob[o];
        float* dst = offs + ((size_t)b * 18 + o) * 4096 + h * 64 + ms * 16 + lq * 4;
        float4 st = make_float4(acc[0] + bias, acc[1] + bias, acc[2] + bias, acc[3] + bias);
        *(float4*)dst = st;
    }
}

// ---------------------------------------------------------------------------
// Kernel 4: implicit-GEMM deformable conv.  Block = one (b,h) row: M=64,
// N=256, K=2304.  512 threads = 8 waves; wave wv owns N-slice [wv*32,+32).
// Bilinear params live in registers (lane = position) and are broadcast via
// __shfl.  A_lds double-buffered: one __syncthreads per tap; next tap's
// gather loads are issued before the current tap's MFMA.
// ---------------------------------------------------------------------------
__device__ __forceinline__ void tap_params(const float* __restrict__ offb, int h, int lane,
                                           int tap, float4& pw, int4& pi) {
    int ki = tap / 3, kj = tap % 3;
    float dy = offb[(tap * 2 + 0) * 4096 + lane];
    float dx = offb[(tap * 2 + 1) * 4096 + lane];
    float py = (float)(h - 1 + ki) + dy;
    float px = (float)(lane - 1 + kj) + dx;
    float y0 = floorf(py), x0 = floorf(px);
    float wy1 = py - y0, wx1 = px - x0;
    float wy0 = 1.f - wy1, wx0 = 1.f - wx1;
    float y1 = y0 + 1.f, x1 = x0 + 1.f;
    float vy0 = (y0 >= 0.f && y0 <= 63.f) ? 1.f : 0.f;
    float vy1 = (y1 >= 0.f && y1 <= 63.f) ? 1.f : 0.f;
    float vx0 = (x0 >= 0.f && x0 <= 63.f) ? 1.f : 0.f;
    float vx1 = (x1 >= 0.f && x1 <= 63.f) ? 1.f : 0.f;
    int iy0 = (int)fminf(fmaxf(y0, 0.f), 63.f);
    int iy1 = (int)fminf(fmaxf(y1, 0.f), 63.f);
    int ix0 = (int)fminf(fmaxf(x0, 0.f), 63.f);
    int ix1 = (int)fminf(fmaxf(x1, 0.f), 63.f);
    pw = make_float4(wy0 * wx0 * vy0 * vx0, wy0 * wx1 * vy0 * vx1,
                     wy1 * wx0 * vy1 * vx0, wy1 * wx1 * vy1 * vx1);
    pi = make_int4((iy0 * 64 + ix0) * 256, (iy0 * 64 + ix1) * 256,
                   (iy1 * 64 + ix0) * 256, (iy1 * 64 + ix1) * 256);
}

__device__ __forceinline__ void tap_gather(const unsigned short* __restrict__ xtb,
                                           unsigned short* __restrict__ Ab,
                                           int wv, int lane, float4 pw, int4 pi) {
    int c0 = lane * 4;
#pragma unroll
    for (int i = 0; i < 8; ++i) {
        int pos = i * 8 + wv;
        float w0 = __shfl(pw.x, pos);
        float w1 = __shfl(pw.y, pos);
        float w2 = __shfl(pw.z, pos);
        float w3 = __shfl(pw.w, pos);
        int o0 = __shfl(pi.x, pos);
        int o1 = __shfl(pi.y, pos);
        int o2 = __shfl(pi.z, pos);
        int o3 = __shfl(pi.w, pos);
        ushort4 a00 = *(const ushort4*)&xtb[o0 + c0];
        ushort4 a01 = *(const ushort4*)&xtb[o1 + c0];
        ushort4 a10 = *(const ushort4*)&xtb[o2 + c0];
        ushort4 a11 = *(const ushort4*)&xtb[o3 + c0];
        float r0 = w0 * bf2f(a00.x) + w1 * bf2f(a01.x) + w2 * bf2f(a10.x) + w3 * bf2f(a11.x);
        float r1 = w0 * bf2f(a00.y) + w1 * bf2f(a01.y) + w2 * bf2f(a10.y) + w3 * bf2f(a11.y);
        float r2 = w0 * bf2f(a00.z) + w1 * bf2f(a01.z) + w2 * bf2f(a10.z) + w3 * bf2f(a11.z);
        float r3 = w0 * bf2f(a00.w) + w1 * bf2f(a01.w) + w2 * bf2f(a10.w) + w3 * bf2f(a11.w);
        ushort4 res = make_ushort4(f2bf(r0), f2bf(r1), f2bf(r2), f2bf(r3));
        *(ushort4*)&Ab[pos * 264 + c0] = res;
    }
}

__global__ __launch_bounds__(512, 2) void deform_kernel(
    const unsigned short* __restrict__ xT,
    const unsigned short* __restrict__ Wp2,
    const float* __restrict__ offs,
    const float* __restrict__ db,
    float* __restrict__ out)
{
    __shared__ unsigned short A_lds[2][64 * 264];   // [pos][c], +8 pad

    int blk = blockIdx.x;
    int b = blk >> 6, h = blk & 63;
    int t = threadIdx.x;
    int wv = t >> 6, lane = t & 63;
    int lq = lane >> 4, ln = lane & 15;

    const unsigned short* xtb = xT + (size_t)b * (64 * 64 * 256);
    const float* offb = offs + (size_t)b * 18 * 4096 + h * 64;

    f32x4 acc[4][2];
#pragma unroll
    for (int ms = 0; ms < 4; ++ms)
#pragma unroll
        for (int ns = 0; ns < 2; ++ns)
            acc[ms][ns] = (f32x4){0.f, 0.f, 0.f, 0.f};

    float4 pw; int4 pi;
    tap_params(offb, h, lane, 0, pw, pi);
    tap_gather(xtb, A_lds[0], wv, lane, pw, pi);
    __syncthreads();

    for (int tap = 0; tap < 9; ++tap) {
        if (tap < 8) {
            tap_params(offb, h, lane, tap + 1, pw, pi);
            tap_gather(xtb, A_lds[(tap + 1) & 1], wv, lane, pw, pi);
        }
        const unsigned short* Ab = A_lds[tap & 1];
#pragma unroll 2
        for (int kc = 0; kc < 8; ++kc) {
            bf16x8 af[4];
#pragma unroll
            for (int ms = 0; ms < 4; ++ms)
                af[ms] = *(const bf16x8*)&Ab[(ms * 16 + ln) * 264 + kc * 32 + lq * 8];
            int kg = tap * 8 + kc;
            bf16x8 bfr[2];
#pragma unroll
            for (int ns = 0; ns < 2; ++ns) {
                int n = wv * 32 + ns * 16 + ln;
                bfr[ns] = *(const bf16x8*)&Wp2[(((kg * 4 + lq) * 256) + n) * 8];
            }
#pragma unroll
            for (int ms = 0; ms < 4; ++ms)
#pragma unroll
                for (int ns = 0; ns < 2; ++ns)
                    acc[ms][ns] = __builtin_amdgcn_mfma_f32_16x16x32_bf16(af[ms], bfr[ns], acc[ms][ns], 0, 0, 0);
        }
        __syncthreads();
    }
    // ---- epilogue: D layout col=ln -> o, row=lq*4+r -> w
#pragma unroll
    for (int ns = 0; ns < 2; ++ns) {
        int o = wv * 32 + ns * 16 + ln;
        float bias = db[o];
        float* ob = out + (size_t)(b * 256 + o) * 4096 + h * 64;
#pragma unroll
        for (int ms = 0; ms < 4; ++ms) {
            int wb = ms * 16 + lq * 4;
            float4 st = make_float4(acc[ms][ns][0] + bias, acc[ms][ns][1] + bias,
                                    acc[ms][ns][2] + bias, acc[ms][ns][3] + bias);
            *(float4*)&ob[wb] = st;
        }
    }
}

extern "C" void kernel_launch(void* const* d_in, const int* in_sizes, int n_in,
                              void* d_out, int out_size, void* d_ws, size_t ws_size,
                              hipStream_t stream) {
    const float* x  = (const float*)d_in[0];
    const float* y  = (const float*)d_in[1];
    const float* ow = (const float*)d_in[2];
    const float* ob = (const float*)d_in[3];
    const float* dw = (const float*)d_in[4];
    const float* db = (const float*)d_in[5];
    float* out = (float*)d_out;

    char* ws = (char*)d_ws;
    unsigned short* xT  = (unsigned short*)(ws);
    unsigned short* yT  = (unsigned short*)(ws + 8388608);
    unsigned short* Wp2 = (unsigned short*)(ws + 16777216);
    unsigned short* Bo  = (unsigned short*)(ws + 16777216 + 1179648);
    float*          offs = (float*)(ws + 16777216 + 1179648 + 147456);

    hipLaunchKernelGGL(xpose_kernel, dim3(1024), dim3(256), 0, stream, x, xT);
    hipLaunchKernelGGL(xpose_kernel, dim3(1024), dim3(256), 0, stream, y, yT);
    hipLaunchKernelGGL(packw_kernel, dim3(2304), dim3(256), 0, stream, dw, Wp2);
    hipLaunchKernelGGL(packow_kernel, dim3(288), dim3(256), 0, stream, ow, Bo);
    hipLaunchKernelGGL(offs_mfma_kernel, dim3(256), dim3(512), 0, stream, yT, Bo, ob, offs);
    hipLaunchKernelGGL(deform_kernel, dim3(256), dim3(512), 0, stream, xT, Wp2, offs, db, out);
}

// Round 3
// 144.327 us; speedup vs baseline: 1.7053x; 1.2397x over previous
//
#include <hip/hip_runtime.h>
#include <hip/hip_bf16.h>
#include <stdint.h>

// Problem: B=4, C=256, O=256, H=W=64, K=3, K2=9, KK=2304
// ws: xT bf16 NHWC @0 (8388608) | yT @8388608 (8388608) | Wp2 @16777216
//     (1179648) | Bo (+147456) | offs fp32 (+1179648)

typedef __bf16 bf16x8 __attribute__((ext_vector_type(8)));
typedef float  f32x4  __attribute__((ext_vector_type(4)));

__device__ __forceinline__ unsigned short f2bfu(float f) {
    union { float f; unsigned u; } v; v.f = f;
    return (unsigned short)((v.u + 0x8000u) >> 16);   // fast round (ties differ from RNE only)
}
__device__ __forceinline__ float lo16(unsigned u) {
    union { unsigned u; float f; } v; v.u = u << 16; return v.f;
}
__device__ __forceinline__ float hi16(unsigned u) {
    union { unsigned u; float f; } v; v.u = u & 0xFFFF0000u; return v.f;
}
__device__ __forceinline__ unsigned fbits(float f) {
    union { float f; unsigned u; } v; v.f = f; return v.u;
}
// 2-channel bilinear blend: dword in (ch_lo | ch_hi<<16) bf16 pair -> blended bf16 pair
__device__ __forceinline__ unsigned blend2(unsigned u0, unsigned u1, unsigned u2, unsigned u3,
                                           float4 w) {
    float lo = w.x * lo16(u0) + w.y * lo16(u1) + w.z * lo16(u2) + w.w * lo16(u3);
    float hi = w.x * hi16(u0) + w.y * hi16(u1) + w.z * hi16(u2) + w.w * hi16(u3);
    unsigned rl = fbits(lo) + 0x8000u;
    unsigned rh = fbits(hi) + 0x8000u;
    return __builtin_amdgcn_perm(rh, rl, 0x07060302);  // {rh[3],rh[2],rl[3],rl[2]}
}

// ---------------------------------------------------------------------------
// Kernel 1: fused transpose x->xT, y->yT.  (B,C,H,W) f32 -> (B,H,W,C) bf16.
// Block = (src, b, h, cq).  float4 reads, f32 LDS tile (pad 69), ushort4 writes.
// ---------------------------------------------------------------------------
__global__ __launch_bounds__(256) void xpose2_kernel(const float* __restrict__ x,
                                                     const float* __restrict__ y,
                                                     unsigned short* __restrict__ xT,
                                                     unsigned short* __restrict__ yT) {
    __shared__ float tile[64 * 69];
    int blk = blockIdx.x;
    const float* src = x; unsigned short* dst = xT;
    if (blk >= 1024) { src = y; dst = yT; blk -= 1024; }
    int cq = blk & 3;
    int bh = blk >> 2;
    int t = threadIdx.x;
    int w4 = t & 15, cl0 = t >> 4;
    const float* s = src + ((size_t)(bh >> 6) * 256 + cq * 64) * 4096 + (size_t)(bh & 63) * 64;
#pragma unroll
    for (int p = 0; p < 4; ++p) {
        int cl = p * 16 + cl0;
        float4 v = *(const float4*)&s[(size_t)cl * 4096 + w4 * 4];
        tile[(w4 * 4 + 0) * 69 + cl] = v.x;
        tile[(w4 * 4 + 1) * 69 + cl] = v.y;
        tile[(w4 * 4 + 2) * 69 + cl] = v.z;
        tile[(w4 * 4 + 3) * 69 + cl] = v.w;
    }
    __syncthreads();
    unsigned short* d = dst + (size_t)bh * 16384 + cq * 64;
#pragma unroll
    for (int p = 0; p < 4; ++p) {
        int w = p * 16 + cl0;
        float4 v = *(const float4*)&tile[w * 69 + w4 * 4];
        ushort4 r = make_ushort4(f2bfu(v.x), f2bfu(v.y), f2bfu(v.z), f2bfu(v.w));
        *(ushort4*)&d[w * 256 + w4 * 4] = r;
    }
}

// ---------------------------------------------------------------------------
// Kernel 2: deform_w -> Wp2, dst-indexed (coalesced 16B writes).
// Wp2[(q8*256 + o)*8 + j] = W[o][k = q8*8+j], k = tap*256 + c.
// ---------------------------------------------------------------------------
__global__ __launch_bounds__(256) void packw_kernel(const float* __restrict__ dw,
                                                    unsigned short* __restrict__ Wp2) {
    int tid = blockIdx.x * 256 + threadIdx.x;   // 288 blocks -> 73728 threads
    int q8 = tid >> 8;
    int o  = tid & 255;
    int k0 = q8 * 8;
    int tap = k0 >> 8, c0 = k0 & 255;
    const float* s = dw + o * 2304 + c0 * 9 + tap;
    ushort4 r0 = make_ushort4(f2bfu(s[0]), f2bfu(s[9]), f2bfu(s[18]), f2bfu(s[27]));
    ushort4 r1 = make_ushort4(f2bfu(s[36]), f2bfu(s[45]), f2bfu(s[54]), f2bfu(s[63]));
    *(ushort4*)&Wp2[tid * 8 + 0] = r0;
    *(ushort4*)&Wp2[tid * 8 + 4] = r1;
}

// ---------------------------------------------------------------------------
// Kernel 2b: offset_w -> Bo (B-fragment order, N padded to 32).  Unchanged.
// ---------------------------------------------------------------------------
__global__ __launch_bounds__(256) void packow_kernel(const float* __restrict__ ow,
                                                     unsigned short* __restrict__ Bo) {
    int idx = blockIdx.x * 256 + threadIdx.x;   // 288 blocks
    int j = idx & 7;
    int n = (idx >> 3) & 31;
    int lq = (idx >> 8) & 3;
    int kg = idx >> 10;                // 0..71
    int k = kg * 32 + lq * 8 + j;
    int tap = k >> 8, c = k & 255;
    float v = (n < 18) ? ow[n * 2304 + c * 9 + tap] : 0.f;
    Bo[idx] = f2bfu(v);
}

// ---------------------------------------------------------------------------
// Kernel 3: offsets conv, MFMA, 3 yT rows staged in LDS (w-padded, swizzled).
// Block = (b,h); 512 thr = 8 waves (mh = M-half, kq = K-quarter); LDS reduce.
// ---------------------------------------------------------------------------
__global__ __launch_bounds__(512) void offs_mfma_kernel(
    const unsigned short* __restrict__ yT,
    const unsigned short* __restrict__ Bo,
    const float* __restrict__ ob,
    float* __restrict__ offs)
{
    __shared__ unsigned short yr[3 * 66 * 256];   // 101376 B
    float* red = (float*)yr;                      // reuse after barrier (24576 B)

    int blk = blockIdx.x;
    int b = blk >> 6, h = blk & 63;
    int t = threadIdx.x;

    // stage rows h-1..h+1, w-padded (wp = w+1, zeros at wp=0,65), granule-swizzled
#pragma unroll
    for (int r = 0; r < 3; ++r) {
        int hr = h + r - 1;
        bool rowok = (hr >= 0) && (hr < 64);
        const unsigned short* src = yT + (size_t)(b * 64 + (hr & 63)) * 64 * 256;
        for (int g = t; g < 2112; g += 512) {       // 66*32 granules
            int wp = g >> 5, gi = g & 31;
            uint4 v = make_uint4(0, 0, 0, 0);
            if (rowok && wp >= 1 && wp <= 64)
                v = *(const uint4*)&src[(wp - 1) * 256 + gi * 8];
            *(uint4*)&yr[(r * 66 + wp) * 256 + (gi ^ (wp & 7)) * 8] = v;
        }
    }
    __syncthreads();

    int wv = t >> 6, lane = t & 63;
    int mh = wv & 1, kq = wv >> 1;     // M-half, K-quarter
    int ln = lane & 15, lq = lane >> 4;

    f32x4 acc[2][2];
#pragma unroll
    for (int ms = 0; ms < 2; ++ms)
#pragma unroll
        for (int nt = 0; nt < 2; ++nt)
            acc[ms][nt] = (f32x4){0.f, 0.f, 0.f, 0.f};

    for (int u = kq; u < 72; u += 4) {           // unit = (tap, kc32)
        int tap = u >> 3, kc = u & 7;
        int ki = tap / 3, kj = tap - ki * 3;
        int gb = kc * 4 + lq;
        bf16x8 af[2];
#pragma unroll
        for (int ms = 0; ms < 2; ++ms) {
            int wp = mh * 32 + ms * 16 + ln + kj;     // 0..65
            af[ms] = *(const bf16x8*)&yr[(ki * 66 + wp) * 256 + (gb ^ (wp & 7)) * 8];
        }
        bf16x8 bfr[2];
#pragma unroll
        for (int nt = 0; nt < 2; ++nt)
            bfr[nt] = *(const bf16x8*)&Bo[(tap * 8 + kc) * 1024 + lq * 256 + (nt * 16 + ln) * 8];
#pragma unroll
        for (int ms = 0; ms < 2; ++ms)
#pragma unroll
            for (int nt = 0; nt < 2; ++nt)
                acc[ms][nt] = __builtin_amdgcn_mfma_f32_16x16x32_bf16(af[ms], bfr[nt], acc[ms][nt], 0, 0, 0);
    }

    __syncthreads();   // all yr reads done before red overwrites
    if (kq > 0) {
        float* rg = red + (size_t)((mh * 3 + (kq - 1)) * 4) * 256;
#pragma unroll
        for (int ms = 0; ms < 2; ++ms)
#pragma unroll
            for (int nt = 0; nt < 2; ++nt)
#pragma unroll
                for (int r = 0; r < 4; ++r)
                    rg[(ms * 2 + nt) * 256 + (lq * 4 + r) * 16 + ln] = acc[ms][nt][r];
    }
    __syncthreads();
    if (kq == 0) {
#pragma unroll
        for (int ms = 0; ms < 2; ++ms)
#pragma unroll
            for (int nt = 0; nt < 2; ++nt) {
                int o = nt * 16 + ln;
                f32x4 s = acc[ms][nt];
#pragma unroll
                for (int kk = 0; kk < 3; ++kk) {
                    const float* rg = red + (size_t)((mh * 3 + kk) * 4 + ms * 2 + nt) * 256;
#pragma unroll
                    for (int r = 0; r < 4; ++r)
                        s[r] += rg[(lq * 4 + r) * 16 + ln];
                }
                if (o < 18) {
                    float bias = ob[o];
                    float* dst = offs + ((size_t)b * 18 + o) * 4096 + h * 64 + mh * 32 + ms * 16 + lq * 4;
                    float4 st = make_float4(s[0] + bias, s[1] + bias, s[2] + bias, s[3] + bias);
                    *(float4*)dst = st;
                }
            }
    }
}

// ---------------------------------------------------------------------------
// Kernel 4: deformable conv implicit GEMM.  Block = (b,h): M=64, N=256, K=2304.
// 8 waves = (ns = N-quarter of 64, kh = K-half) -> A LDS reads halved vs N=32
// slices; Wp2 read exactly once per block.  Params for all 9 taps precomputed
// in LDS prologue.  A dbuf XOR-swizzled (conflict-free b128).  K-half partials
// reduced via LDS epilogue.
// ---------------------------------------------------------------------------
__device__ __forceinline__ void gather_tap(const unsigned short* __restrict__ xtb,
                                           unsigned short* __restrict__ buf,
                                           const float4* __restrict__ pw_lds,
                                           const int4* __restrict__ pi_lds,
                                           int tap, int wv, int lane) {
    int p2 = lane >> 5, cl = lane & 31;
    int c0 = cl * 8;
    int base = tap * 64 + wv * 2 + p2;
    float4 w = pw_lds[base];
    int4  pi = pi_lds[base];
    uint4 a00 = *(const uint4*)&xtb[pi.x + c0];
    uint4 a01 = *(const uint4*)&xtb[pi.y + c0];
    uint4 a10 = *(const uint4*)&xtb[pi.z + c0];
    uint4 a11 = *(const uint4*)&xtb[pi.w + c0];
#pragma unroll
    for (int i = 0; i < 4; ++i) {
        uint4 b00, b01, b10, b11; float4 wn; int4 pin;
        if (i < 3) {                       // prefetch next position pair
            wn  = pw_lds[base + (i + 1) * 16];
            pin = pi_lds[base + (i + 1) * 16];
            b00 = *(const uint4*)&xtb[pin.x + c0];
            b01 = *(const uint4*)&xtb[pin.y + c0];
            b10 = *(const uint4*)&xtb[pin.z + c0];
            b11 = *(const uint4*)&xtb[pin.w + c0];
        }
        int pos = i * 16 + wv * 2 + p2;
        uint4 res;
        res.x = blend2(a00.x, a01.x, a10.x, a11.x, w);
        res.y = blend2(a00.y, a01.y, a10.y, a11.y, w);
        res.z = blend2(a00.z, a01.z, a10.z, a11.z, w);
        res.w = blend2(a00.w, a01.w, a10.w, a11.w, w);
        *(uint4*)&buf[pos * 256 + (cl ^ (pos & 7)) * 8] = res;
        if (i < 3) { a00 = b00; a01 = b01; a10 = b10; a11 = b11; w = wn; pi = pin; }
    }
}

__global__ __launch_bounds__(512, 2) void deform_kernel(
    const unsigned short* __restrict__ xT,
    const unsigned short* __restrict__ Wp2,
    const float* __restrict__ offs,
    const float* __restrict__ db,
    float* __restrict__ out)
{
    __shared__ unsigned char smem[86016];
    unsigned short* Abuf0 = (unsigned short*)smem;            // 32768 B
    unsigned short* Abuf1 = (unsigned short*)(smem + 32768);  // 32768 B
    float* epi = (float*)smem;                                 // 67584 B (after final barrier)
    float4* pw_lds = (float4*)(smem + 67584);                  // 9216 B
    int4*   pi_lds = (int4*)(smem + 67584 + 9216);             // 9216 B

    int blk = blockIdx.x;
    int b = blk >> 6, h = blk & 63;
    int t = threadIdx.x;
    int wv = t >> 6, lane = t & 63;
    int ln = lane & 15, lq = lane >> 4;
    int ns = wv & 3, kh = wv >> 2;

    const unsigned short* xtb = xT + (size_t)b * (64 * 64 * 256);
    const float* offb = offs + (size_t)b * 18 * 4096 + h * 64;

    // ---- prologue: bilinear params for all (tap, pos)
    for (int job = t; job < 576; job += 512) {
        int tap = job >> 6, pos = job & 63;
        int ki = tap / 3, kj = tap - ki * 3;
        float dy = offb[(tap * 2 + 0) * 4096 + pos];
        float dx = offb[(tap * 2 + 1) * 4096 + pos];
        float py = (float)(h - 1 + ki) + dy;
        float px = (float)(pos - 1 + kj) + dx;
        float y0 = floorf(py), x0 = floorf(px);
        float wy1 = py - y0, wx1 = px - x0;
        float wy0 = 1.f - wy1, wx0 = 1.f - wx1;
        float y1 = y0 + 1.f, x1 = x0 + 1.f;
        float vy0 = (y0 >= 0.f && y0 <= 63.f) ? 1.f : 0.f;
        float vy1 = (y1 >= 0.f && y1 <= 63.f) ? 1.f : 0.f;
        float vx0 = (x0 >= 0.f && x0 <= 63.f) ? 1.f : 0.f;
        float vx1 = (x1 >= 0.f && x1 <= 63.f) ? 1.f : 0.f;
        int iy0 = (int)fminf(fmaxf(y0, 0.f), 63.f);
        int iy1 = (int)fminf(fmaxf(y1, 0.f), 63.f);
        int ix0 = (int)fminf(fmaxf(x0, 0.f), 63.f);
        int ix1 = (int)fminf(fmaxf(x1, 0.f), 63.f);
        pw_lds[job] = make_float4(wy0 * wx0 * vy0 * vx0, wy0 * wx1 * vy0 * vx1,
                                  wy1 * wx0 * vy1 * vx0, wy1 * wx1 * vy1 * vx1);
        pi_lds[job] = make_int4((iy0 * 64 + ix0) * 256, (iy0 * 64 + ix1) * 256,
                                (iy1 * 64 + ix0) * 256, (iy1 * 64 + ix1) * 256);
    }
    __syncthreads();

    f32x4 acc[4][4];
#pragma unroll
    for (int ms = 0; ms < 4; ++ms)
#pragma unroll
        for (int nt = 0; nt < 4; ++nt)
            acc[ms][nt] = (f32x4){0.f, 0.f, 0.f, 0.f};

    gather_tap(xtb, Abuf0, pw_lds, pi_lds, 0, wv, lane);
    __syncthreads();

    for (int tap = 0; tap < 9; ++tap) {
        if (tap < 8)
            gather_tap(xtb, ((tap + 1) & 1) ? Abuf1 : Abuf0, pw_lds, pi_lds, tap + 1, wv, lane);
        const unsigned short* Ab = (tap & 1) ? Abuf1 : Abuf0;
#pragma unroll
        for (int kc = 0; kc < 4; ++kc) {
            int gbase = kh * 16 + kc * 4 + lq;       // channel granule
            bf16x8 af[4];
#pragma unroll
            for (int ms = 0; ms < 4; ++ms) {
                int row = ms * 16 + ln;
                af[ms] = *(const bf16x8*)&Ab[row * 256 + (gbase ^ (row & 7)) * 8];
            }
            int kg = tap * 8 + kh * 4 + kc;
            bf16x8 bfr[4];
#pragma unroll
            for (int nt = 0; nt < 4; ++nt)
                bfr[nt] = *(const bf16x8*)&Wp2[((kg * 4 + lq) * 256 + ns * 64 + nt * 16 + ln) * 8];
#pragma unroll
            for (int ms = 0; ms < 4; ++ms)
#pragma unroll
                for (int nt = 0; nt < 4; ++nt)
                    acc[ms][nt] = __builtin_amdgcn_mfma_f32_16x16x32_bf16(af[ms], bfr[nt], acc[ms][nt], 0, 0, 0);
        }
        __syncthreads();
    }

    // ---- epilogue: sum K-halves via LDS, add bias, store
    if (kh == 1) {
        float* e = epi + (size_t)ns * 4224;   // 64*66 floats per ns
#pragma unroll
        for (int ms = 0; ms < 4; ++ms)
#pragma unroll
            for (int nt = 0; nt < 4; ++nt) {
                int o_l = nt * 16 + ln;
                int wb = ms * 16 + lq * 4;
                f32x4 a = acc[ms][nt];
                float4 st = make_float4(a[0], a[1], a[2], a[3]);
                *(float4*)&e[o_l * 66 + wb] = st;
            }
    }
    __syncthreads();
    if (kh == 0) {
        const float* e = epi + (size_t)ns * 4224;
#pragma unroll
        for (int ms = 0; ms < 4; ++ms)
#pragma unroll
            for (int nt = 0; nt < 4; ++nt) {
                int o_l = nt * 16 + ln;
                int o = ns * 64 + o_l;
                int wb = ms * 16 + lq * 4;
                float bias = db[o];
                float4 p = *(const float4*)&e[o_l * 66 + wb];
                f32x4 a = acc[ms][nt];
                float4 st = make_float4(a[0] + p.x + bias, a[1] + p.y + bias,
                                        a[2] + p.z + bias, a[3] + p.w + bias);
                *(float4*)&out[((size_t)(b * 256 + o)) * 4096 + h * 64 + wb] = st;
            }
    }
}

extern "C" void kernel_launch(void* const* d_in, const int* in_sizes, int n_in,
                              void* d_out, int out_size, void* d_ws, size_t ws_size,
                              hipStream_t stream) {
    const float* x  = (const float*)d_in[0];
    const float* y  = (const float*)d_in[1];
    const float* ow = (const float*)d_in[2];
    const float* ob = (const float*)d_in[3];
    const float* dw = (const float*)d_in[4];
    const float* db = (const float*)d_in[5];
    float* out = (float*)d_out;

    char* ws = (char*)d_ws;
    unsigned short* xT  = (unsigned short*)(ws);
    unsigned short* yT  = (unsigned short*)(ws + 8388608);
    unsigned short* Wp2 = (unsigned short*)(ws + 16777216);
    unsigned short* Bo  = (unsigned short*)(ws + 16777216 + 1179648);
    float*          offs = (float*)(ws + 16777216 + 1179648 + 147456);

    hipLaunchKernelGGL(xpose2_kernel, dim3(2048), dim3(256), 0, stream, x, y, xT, yT);
    hipLaunchKernelGGL(packw_kernel, dim3(288), dim3(256), 0, stream, dw, Wp2);
    hipLaunchKernelGGL(packow_kernel, dim3(288), dim3(256), 0, stream, ow, Bo);
    hipLaunchKernelGGL(offs_mfma_kernel, dim3(256), dim3(512), 0, stream, yT, Bo, ob, offs);
    hipLaunchKernelGGL(deform_kernel, dim3(256), dim3(512), 0, stream, xT, Wp2, offs, db, out);
}

// Round 4
// 137.354 us; speedup vs baseline: 1.7919x; 1.0508x over previous
//
#include <hip/hip_runtime.h>
#include <hip/hip_bf16.h>
#include <stdint.h>

// Problem: B=4, C=256, O=256, H=W=64, K=3, K2=9, KK=2304
// ws: xT bf16 NHWC @0 (8388608) | yT @8388608 (8388608) | Wp2 @16777216
//     (1179648) | Bo (+147456) | offs fp32 (+1179648)

typedef __bf16 bf16x8 __attribute__((ext_vector_type(8)));
typedef float  f32x4  __attribute__((ext_vector_type(4)));

__device__ __forceinline__ unsigned short f2bfu(float f) {
    union { float f; unsigned u; } v; v.f = f;
    return (unsigned short)((v.u + 0x8000u) >> 16);
}
__device__ __forceinline__ float lo16(unsigned u) {
    union { unsigned u; float f; } v; v.u = u << 16; return v.f;
}
__device__ __forceinline__ float hi16(unsigned u) {
    union { unsigned u; float f; } v; v.u = u & 0xFFFF0000u; return v.f;
}
__device__ __forceinline__ unsigned fbits(float f) {
    union { float f; unsigned u; } v; v.f = f; return v.u;
}
__device__ __forceinline__ unsigned blend2(unsigned u0, unsigned u1, unsigned u2, unsigned u3,
                                           float4 w) {
    float lo = w.x * lo16(u0) + w.y * lo16(u1) + w.z * lo16(u2) + w.w * lo16(u3);
    float hi = w.x * hi16(u0) + w.y * hi16(u1) + w.z * hi16(u2) + w.w * hi16(u3);
    unsigned rl = fbits(lo) + 0x8000u;
    unsigned rh = fbits(hi) + 0x8000u;
    return __builtin_amdgcn_perm(rh, rl, 0x07060302);
}

// ---------------------------------------------------------------------------
// prep: fused {x,y transpose to NHWC bf16} + {packw} + {packow}.
// grid 2624 x 256: blk<2048 xpose (x then y), 2048..2335 packw, 2336.. packow
// ---------------------------------------------------------------------------
__global__ __launch_bounds__(256) void prep_kernel(
    const float* __restrict__ x, const float* __restrict__ y,
    const float* __restrict__ ow, const float* __restrict__ dw,
    unsigned short* __restrict__ xT, unsigned short* __restrict__ yT,
    unsigned short* __restrict__ Wp2, unsigned short* __restrict__ Bo)
{
    __shared__ float tile[64 * 69];
    int blk = blockIdx.x;
    int t = threadIdx.x;
    if (blk < 2048) {
        const float* src = x; unsigned short* dst = xT;
        if (blk >= 1024) { src = y; dst = yT; blk -= 1024; }
        int cq = blk & 3;
        int bh = blk >> 2;
        int w4 = t & 15, cl0 = t >> 4;
        const float* s = src + ((size_t)(bh >> 6) * 256 + cq * 64) * 4096 + (size_t)(bh & 63) * 64;
#pragma unroll
        for (int p = 0; p < 4; ++p) {
            int cl = p * 16 + cl0;
            float4 v = *(const float4*)&s[(size_t)cl * 4096 + w4 * 4];
            tile[(w4 * 4 + 0) * 69 + cl] = v.x;
            tile[(w4 * 4 + 1) * 69 + cl] = v.y;
            tile[(w4 * 4 + 2) * 69 + cl] = v.z;
            tile[(w4 * 4 + 3) * 69 + cl] = v.w;
        }
        __syncthreads();
        unsigned short* d = dst + (size_t)bh * 16384 + cq * 64;
#pragma unroll
        for (int p = 0; p < 4; ++p) {
            int w = p * 16 + cl0;
            float4 v = *(const float4*)&tile[w * 69 + w4 * 4];
            ushort4 r = make_ushort4(f2bfu(v.x), f2bfu(v.y), f2bfu(v.z), f2bfu(v.w));
            *(ushort4*)&d[w * 256 + w4 * 4] = r;
        }
    } else if (blk < 2336) {
        // packw: Wp2[(q8*256 + o)*8 + j] = W[o][k=q8*8+j], k = tap*256+c
        int tid = (blk - 2048) * 256 + t;
        int q8 = tid >> 8;
        int o  = tid & 255;
        int k0 = q8 * 8;
        int tap = k0 >> 8, c0 = k0 & 255;
        const float* s = dw + o * 2304 + c0 * 9 + tap;
        ushort4 r0 = make_ushort4(f2bfu(s[0]), f2bfu(s[9]), f2bfu(s[18]), f2bfu(s[27]));
        ushort4 r1 = make_ushort4(f2bfu(s[36]), f2bfu(s[45]), f2bfu(s[54]), f2bfu(s[63]));
        *(ushort4*)&Wp2[tid * 8 + 0] = r0;
        *(ushort4*)&Wp2[tid * 8 + 4] = r1;
    } else {
        // packow: Bo[kg*1024 + lq*256 + n*8 + j], N padded to 32
        int idx = (blk - 2336) * 256 + t;
        int j = idx & 7;
        int n = (idx >> 3) & 31;
        int lq = (idx >> 8) & 3;
        int kg = idx >> 10;
        int k = kg * 32 + lq * 8 + j;
        int tap = k >> 8, c = k & 255;
        float v = (n < 18) ? ow[n * 2304 + c * 9 + tap] : 0.f;
        Bo[idx] = f2bfu(v);
    }
}

// ---------------------------------------------------------------------------
// offsets conv via MFMA.  Grid 512 = (b,h,mh): M=32 (w in [mh*32,+32)),
// N=32(18), K=2304.  Stage 3 rows x 34 wp x 256c bf16 (52 KB, swizzled) ->
// 2-3 blocks/CU.  8 waves = (kq = K-quarter, m16 = M-16-half); LDS reduce.
// ---------------------------------------------------------------------------
__global__ __launch_bounds__(512, 4) void offs_mfma_kernel(
    const unsigned short* __restrict__ yT,
    const unsigned short* __restrict__ Bo,
    const float* __restrict__ ob,
    float* __restrict__ offs)
{
    __shared__ __align__(16) unsigned char ysm[52224];
    unsigned short* yr = (unsigned short*)ysm;
    float* red = (float*)ysm;

    int blk = blockIdx.x;
    int lb = (blk & 7) * 64 + (blk >> 3);        // XCD-slab swizzle
    int b = lb >> 7, rem = lb & 127, h = rem >> 1, mh = rem & 1;
    int t = threadIdx.x;

    // stage rows h-1..h+1, wp = 0..33 -> w = mh*32 + wp - 1
    for (unsigned g = t; g < 3264; g += 512) {
        unsigned r = g / 1088;
        unsigned rm = g - r * 1088;
        int wp = rm >> 5, gr = rm & 31;
        int hr = h + (int)r - 1;
        int w = mh * 32 + wp - 1;
        uint4 v = make_uint4(0, 0, 0, 0);
        if (hr >= 0 && hr < 64 && w >= 0 && w < 64)
            v = *(const uint4*)&yT[((size_t)(b * 64 + hr) * 64 + w) * 256 + gr * 8];
        *(uint4*)&yr[((r * 34) + wp) * 256 + (gr ^ (wp & 7)) * 8] = v;
    }
    __syncthreads();

    int wv = t >> 6, lane = t & 63;
    int kq = wv >> 1, m16 = wv & 1;
    int ln = lane & 15, lq = lane >> 4;

    f32x4 acc[2];
    acc[0] = (f32x4){0.f, 0.f, 0.f, 0.f};
    acc[1] = (f32x4){0.f, 0.f, 0.f, 0.f};

    for (int u = kq; u < 72; u += 4) {
        int tap = u >> 3, kc = u & 7;
        int ki = tap / 3, kj = tap - ki * 3;
        int wp = m16 * 16 + ln + kj;             // 0..33
        bf16x8 af = *(const bf16x8*)&yr[(ki * 34 + wp) * 256 + ((kc * 4 + lq) ^ (wp & 7)) * 8];
        bf16x8 b0 = *(const bf16x8*)&Bo[(tap * 8 + kc) * 1024 + lq * 256 + ln * 8];
        bf16x8 b1 = *(const bf16x8*)&Bo[(tap * 8 + kc) * 1024 + lq * 256 + (16 + ln) * 8];
        acc[0] = __builtin_amdgcn_mfma_f32_16x16x32_bf16(af, b0, acc[0], 0, 0, 0);
        acc[1] = __builtin_amdgcn_mfma_f32_16x16x32_bf16(af, b1, acc[1], 0, 0, 0);
    }

    __syncthreads();
    if (kq > 0) {
        float* rg = red + (size_t)(((kq - 1) * 2 + m16) * 2) * 256;
#pragma unroll
        for (int nt = 0; nt < 2; ++nt)
#pragma unroll
            for (int r = 0; r < 4; ++r)
                rg[nt * 256 + (lq * 4 + r) * 16 + ln] = acc[nt][r];
    }
    __syncthreads();
    if (kq == 0) {
#pragma unroll
        for (int nt = 0; nt < 2; ++nt) {
            int o = nt * 16 + ln;
            f32x4 s = acc[nt];
#pragma unroll
            for (int kk = 0; kk < 3; ++kk) {
                const float* rg = red + (size_t)((kk * 2 + m16) * 2 + nt) * 256;
#pragma unroll
                for (int r = 0; r < 4; ++r)
                    s[r] += rg[(lq * 4 + r) * 16 + ln];
            }
            if (o < 18) {
                float bias = ob[o];
                float* dst = offs + ((size_t)b * 18 + o) * 4096 + h * 64 + mh * 32 + m16 * 16 + lq * 4;
                *(float4*)dst = make_float4(s[0] + bias, s[1] + bias, s[2] + bias, s[3] + bias);
            }
        }
    }
}

// ---------------------------------------------------------------------------
// deform: implicit GEMM.  Grid 512 = (b,h,mh): M=32, N=256, K=2304.
// 8 waves = (ns = N-quarter, kh = K-half).  Per tap, per wave:
//   phase1 issue 8 uint4 gather loads (regs) -> phase2 MFMA current tap
//   -> phase3 blend+store next tap.  MFMA hides the gather-load latency.
// LDS 41 KB -> 2 blocks/CU co-resident.
// ---------------------------------------------------------------------------
__device__ __forceinline__ void gather_issue(const unsigned short* __restrict__ xtb,
                                             const float4* __restrict__ pw_lds,
                                             const int4* __restrict__ pi_lds,
                                             int tap, int t, uint4 a[2][4], float4 wr[2]) {
    int gr = t & 31, c0 = gr * 8;
#pragma unroll
    for (int it = 0; it < 2; ++it) {
        int pos = (t >> 5) + it * 16;
        wr[it] = pw_lds[tap * 32 + pos];
        int4 p = pi_lds[tap * 32 + pos];
        a[it][0] = *(const uint4*)&xtb[p.x + c0];
        a[it][1] = *(const uint4*)&xtb[p.y + c0];
        a[it][2] = *(const uint4*)&xtb[p.z + c0];
        a[it][3] = *(const uint4*)&xtb[p.w + c0];
    }
}
__device__ __forceinline__ void gather_commit(unsigned short* __restrict__ buf,
                                              int t, uint4 a[2][4], float4 wr[2]) {
    int gr = t & 31;
#pragma unroll
    for (int it = 0; it < 2; ++it) {
        int pos = (t >> 5) + it * 16;
        uint4 res;
        res.x = blend2(a[it][0].x, a[it][1].x, a[it][2].x, a[it][3].x, wr[it]);
        res.y = blend2(a[it][0].y, a[it][1].y, a[it][2].y, a[it][3].y, wr[it]);
        res.z = blend2(a[it][0].z, a[it][1].z, a[it][2].z, a[it][3].z, wr[it]);
        res.w = blend2(a[it][0].w, a[it][1].w, a[it][2].w, a[it][3].w, wr[it]);
        *(uint4*)&buf[pos * 256 + (gr ^ (pos & 7)) * 8] = res;
    }
}

__global__ __launch_bounds__(512, 4) void deform_kernel(
    const unsigned short* __restrict__ xT,
    const unsigned short* __restrict__ Wp2,
    const float* __restrict__ offs,
    const float* __restrict__ db,
    float* __restrict__ out)
{
    __shared__ __align__(16) unsigned char smem[41984];
    unsigned short* Abuf0 = (unsigned short*)smem;             // 16384 B
    unsigned short* Abuf1 = (unsigned short*)(smem + 16384);   // 16384 B
    float4* pw_lds = (float4*)(smem + 32768);                  // 4608 B
    int4*   pi_lds = (int4*)(smem + 32768 + 4608);             // 4608 B
    float*  epi    = (float*)smem;                             // 32768 B reuse

    int blk = blockIdx.x;
    int lb = (blk & 7) * 64 + (blk >> 3);        // XCD-slab swizzle
    int b = lb >> 7, rem = lb & 127, h = rem >> 1, mh = rem & 1;
    int t = threadIdx.x;
    int wv = t >> 6, lane = t & 63;
    int ln = lane & 15, lq = lane >> 4;
    int ns = wv & 3, kh = wv >> 2;

    const unsigned short* xtb = xT + (size_t)b * (64 * 64 * 256);
    const float* offb = offs + (size_t)b * 18 * 4096 + h * 64;

    // ---- prologue: bilinear params for 9 taps x 32 local positions
    if (t < 288) {
        int tap = t >> 5, pos_l = t & 31;
        int pos_g = mh * 32 + pos_l;
        int ki = tap / 3, kj = tap - ki * 3;
        float dy = offb[(tap * 2 + 0) * 4096 + pos_g];
        float dx = offb[(tap * 2 + 1) * 4096 + pos_g];
        float py = (float)(h - 1 + ki) + dy;
        float px = (float)(pos_g - 1 + kj) + dx;
        float y0 = floorf(py), x0 = floorf(px);
        float wy1 = py - y0, wx1 = px - x0;
        float wy0 = 1.f - wy1, wx0 = 1.f - wx1;
        float y1 = y0 + 1.f, x1 = x0 + 1.f;
        float vy0 = (y0 >= 0.f && y0 <= 63.f) ? 1.f : 0.f;
        float vy1 = (y1 >= 0.f && y1 <= 63.f) ? 1.f : 0.f;
        float vx0 = (x0 >= 0.f && x0 <= 63.f) ? 1.f : 0.f;
        float vx1 = (x1 >= 0.f && x1 <= 63.f) ? 1.f : 0.f;
        int iy0 = (int)fminf(fmaxf(y0, 0.f), 63.f);
        int iy1 = (int)fminf(fmaxf(y1, 0.f), 63.f);
        int ix0 = (int)fminf(fmaxf(x0, 0.f), 63.f);
        int ix1 = (int)fminf(fmaxf(x1, 0.f), 63.f);
        pw_lds[t] = make_float4(wy0 * wx0 * vy0 * vx0, wy0 * wx1 * vy0 * vx1,
                                wy1 * wx0 * vy1 * vx0, wy1 * wx1 * vy1 * vx1);
        pi_lds[t] = make_int4((iy0 * 64 + ix0) * 256, (iy0 * 64 + ix1) * 256,
                              (iy1 * 64 + ix0) * 256, (iy1 * 64 + ix1) * 256);
    }
    __syncthreads();

    f32x4 acc[2][4];
#pragma unroll
    for (int ms = 0; ms < 2; ++ms)
#pragma unroll
        for (int nt = 0; nt < 4; ++nt)
            acc[ms][nt] = (f32x4){0.f, 0.f, 0.f, 0.f};

    uint4 ga[2][4]; float4 gw[2];
    gather_issue(xtb, pw_lds, pi_lds, 0, t, ga, gw);
    gather_commit(Abuf0, t, ga, gw);
    __syncthreads();

    for (int tap = 0; tap < 9; ++tap) {
        // phase 1: issue next tap's gather loads (no use yet)
        if (tap < 8)
            gather_issue(xtb, pw_lds, pi_lds, tap + 1, t, ga, gw);
        // phase 2: MFMA on current tap
        const unsigned short* Ab = (tap & 1) ? Abuf1 : Abuf0;
#pragma unroll
        for (int kc = 0; kc < 4; ++kc) {
            bf16x8 af[2];
#pragma unroll
            for (int ms = 0; ms < 2; ++ms) {
                int row = ms * 16 + ln;
                af[ms] = *(const bf16x8*)&Ab[row * 256 + (((kh * 16 + kc * 4 + lq)) ^ (row & 7)) * 8];
            }
            int kg = tap * 8 + kh * 4 + kc;
            bf16x8 bfr[4];
#pragma unroll
            for (int nt = 0; nt < 4; ++nt)
                bfr[nt] = *(const bf16x8*)&Wp2[((kg * 4 + lq) * 256 + ns * 64 + nt * 16 + ln) * 8];
#pragma unroll
            for (int ms = 0; ms < 2; ++ms)
#pragma unroll
                for (int nt = 0; nt < 4; ++nt)
                    acc[ms][nt] = __builtin_amdgcn_mfma_f32_16x16x32_bf16(af[ms], bfr[nt], acc[ms][nt], 0, 0, 0);
        }
        // phase 3: blend + store next tap
        if (tap < 8)
            gather_commit((tap & 1) ? Abuf0 : Abuf1, t, ga, gw);
        __syncthreads();
    }

    // ---- epilogue: reduce K-halves via LDS (swizzled), bias, store
    if (kh == 1) {
        float* e = epi + (size_t)ns * 2048;
#pragma unroll
        for (int ms = 0; ms < 2; ++ms)
#pragma unroll
            for (int nt = 0; nt < 4; ++nt) {
                int o_l = nt * 16 + ln;
                int g = (ms * 4 + lq) ^ (o_l & 7);
                f32x4 a = acc[ms][nt];
                *(float4*)&e[o_l * 32 + g * 4] = make_float4(a[0], a[1], a[2], a[3]);
            }
    }
    __syncthreads();
    if (kh == 0) {
        const float* e = epi + (size_t)ns * 2048;
#pragma unroll
        for (int ms = 0; ms < 2; ++ms)
#pragma unroll
            for (int nt = 0; nt < 4; ++nt) {
                int o_l = nt * 16 + ln;
                int o = ns * 64 + o_l;
                int g = (ms * 4 + lq) ^ (o_l & 7);
                float bias = db[o];
                float4 p = *(const float4*)&e[o_l * 32 + g * 4];
                f32x4 a = acc[ms][nt];
                int wb = mh * 32 + ms * 16 + lq * 4;
                float4 st = make_float4(a[0] + p.x + bias, a[1] + p.y + bias,
                                        a[2] + p.z + bias, a[3] + p.w + bias);
                *(float4*)&out[((size_t)(b * 256 + o)) * 4096 + h * 64 + wb] = st;
            }
    }
}

extern "C" void kernel_launch(void* const* d_in, const int* in_sizes, int n_in,
                              void* d_out, int out_size, void* d_ws, size_t ws_size,
                              hipStream_t stream) {
    const float* x  = (const float*)d_in[0];
    const float* y  = (const float*)d_in[1];
    const float* ow = (const float*)d_in[2];
    const float* ob = (const float*)d_in[3];
    const float* dw = (const float*)d_in[4];
    const float* db = (const float*)d_in[5];
    float* out = (float*)d_out;

    char* ws = (char*)d_ws;
    unsigned short* xT  = (unsigned short*)(ws);
    unsigned short* yT  = (unsigned short*)(ws + 8388608);
    unsigned short* Wp2 = (unsigned short*)(ws + 16777216);
    unsigned short* Bo  = (unsigned short*)(ws + 16777216 + 1179648);
    float*          offs = (float*)(ws + 16777216 + 1179648 + 147456);

    hipLaunchKernelGGL(prep_kernel, dim3(2624), dim3(256), 0, stream,
                       x, y, ow, dw, xT, yT, Wp2, Bo);
    hipLaunchKernelGGL(offs_mfma_kernel, dim3(512), dim3(512), 0, stream, yT, Bo, ob, offs);
    hipLaunchKernelGGL(deform_kernel, dim3(512), dim3(512), 0, stream, xT, Wp2, offs, db, out);
}

// Round 5
// 135.204 us; speedup vs baseline: 1.8204x; 1.0159x over previous
//
#include <hip/hip_runtime.h>
#include <hip/hip_bf16.h>
#include <stdint.h>

// Problem: B=4, C=256, O=256, H=W=64, K=3, K2=9, KK=2304
// ws: xT bf16 NHWC @0 (8388608) | yT @8388608 (8388608) | Wp2 @16777216
//     (1179648) | Bo (+147456)

typedef __bf16 bf16x8 __attribute__((ext_vector_type(8)));
typedef float  f32x4  __attribute__((ext_vector_type(4)));

__device__ __forceinline__ unsigned short f2bfu(float f) {
    union { float f; unsigned u; } v; v.f = f;
    return (unsigned short)((v.u + 0x8000u) >> 16);
}
__device__ __forceinline__ float lo16(unsigned u) {
    union { unsigned u; float f; } v; v.u = u << 16; return v.f;
}
__device__ __forceinline__ float hi16(unsigned u) {
    union { unsigned u; float f; } v; v.u = u & 0xFFFF0000u; return v.f;
}
__device__ __forceinline__ unsigned fbits(float f) {
    union { float f; unsigned u; } v; v.f = f; return v.u;
}
__device__ __forceinline__ unsigned blend2(unsigned u0, unsigned u1, unsigned u2, unsigned u3,
                                           float4 w) {
    float lo = w.x * lo16(u0) + w.y * lo16(u1) + w.z * lo16(u2) + w.w * lo16(u3);
    float hi = w.x * hi16(u0) + w.y * hi16(u1) + w.z * hi16(u2) + w.w * hi16(u3);
    unsigned rl = fbits(lo) + 0x8000u;
    unsigned rh = fbits(hi) + 0x8000u;
    return __builtin_amdgcn_perm(rh, rl, 0x07060302);
}

// ---------------------------------------------------------------------------
// prep: fused {x,y transpose to NHWC bf16} + {packw} + {packow}.
// ---------------------------------------------------------------------------
__global__ __launch_bounds__(256) void prep_kernel(
    const float* __restrict__ x, const float* __restrict__ y,
    const float* __restrict__ ow, const float* __restrict__ dw,
    unsigned short* __restrict__ xT, unsigned short* __restrict__ yT,
    unsigned short* __restrict__ Wp2, unsigned short* __restrict__ Bo)
{
    __shared__ float tile[64 * 69];
    int blk = blockIdx.x;
    int t = threadIdx.x;
    if (blk < 2048) {
        const float* src = x; unsigned short* dst = xT;
        if (blk >= 1024) { src = y; dst = yT; blk -= 1024; }
        int cq = blk & 3;
        int bh = blk >> 2;
        int w4 = t & 15, cl0 = t >> 4;
        const float* s = src + ((size_t)(bh >> 6) * 256 + cq * 64) * 4096 + (size_t)(bh & 63) * 64;
#pragma unroll
        for (int p = 0; p < 4; ++p) {
            int cl = p * 16 + cl0;
            float4 v = *(const float4*)&s[(size_t)cl * 4096 + w4 * 4];
            tile[(w4 * 4 + 0) * 69 + cl] = v.x;
            tile[(w4 * 4 + 1) * 69 + cl] = v.y;
            tile[(w4 * 4 + 2) * 69 + cl] = v.z;
            tile[(w4 * 4 + 3) * 69 + cl] = v.w;
        }
        __syncthreads();
        unsigned short* d = dst + (size_t)bh * 16384 + cq * 64;
#pragma unroll
        for (int p = 0; p < 4; ++p) {
            int w = p * 16 + cl0;
            float4 v = *(const float4*)&tile[w * 69 + w4 * 4];
            ushort4 r = make_ushort4(f2bfu(v.x), f2bfu(v.y), f2bfu(v.z), f2bfu(v.w));
            *(ushort4*)&d[w * 256 + w4 * 4] = r;
        }
    } else if (blk < 2336) {
        int tid = (blk - 2048) * 256 + t;
        int q8 = tid >> 8;
        int o  = tid & 255;
        int k0 = q8 * 8;
        int tap = k0 >> 8, c0 = k0 & 255;
        const float* s = dw + o * 2304 + c0 * 9 + tap;
        ushort4 r0 = make_ushort4(f2bfu(s[0]), f2bfu(s[9]), f2bfu(s[18]), f2bfu(s[27]));
        ushort4 r1 = make_ushort4(f2bfu(s[36]), f2bfu(s[45]), f2bfu(s[54]), f2bfu(s[63]));
        *(ushort4*)&Wp2[tid * 8 + 0] = r0;
        *(ushort4*)&Wp2[tid * 8 + 4] = r1;
    } else {
        int idx = (blk - 2336) * 256 + t;
        int j = idx & 7;
        int n = (idx >> 3) & 31;
        int lq = (idx >> 8) & 3;
        int kg = idx >> 10;
        int k = kg * 32 + lq * 8 + j;
        int tap = k >> 8, c = k & 255;
        float v = (n < 18) ? ow[n * 2304 + c * 9 + tap] : 0.f;
        Bo[idx] = f2bfu(v);
    }
}

// ---------------------------------------------------------------------------
// Fused deform: grid 256 = (b,h), 1024 threads = 16 waves.
// Prologue: offsets conv (M=64, N=32pad, K=2304) via MFMA, waves=(kq8, mh2);
//   partials -> red LDS -> bilinear params (pw/pi) in LDS.
// Main: implicit GEMM M=64, N=256, K=2304; waves=(ns8 N-32, kh2 K-half);
//   B (Wp2) read exactly once per block.  Per tap: issue gathers(t+1) ->
//   MFMA(t) -> commit(t+1); dbuf A; 1 barrier/tap.
// Epilogue: K-half reduce via LDS, bias, store NCHW.
// ---------------------------------------------------------------------------
__global__ __launch_bounds__(1024) void deform_kernel(
    const unsigned short* __restrict__ xT,
    const unsigned short* __restrict__ yT,
    const unsigned short* __restrict__ Wp2,
    const unsigned short* __restrict__ Bo,
    const float* __restrict__ ob,
    const float* __restrict__ db,
    float* __restrict__ out)
{
    __shared__ __align__(16) unsigned char smem[88064];
    unsigned short* Abuf0 = (unsigned short*)smem;             // 32768 B
    unsigned short* Abuf1 = (unsigned short*)(smem + 32768);   // 32768 B
    float*  red = (float*)smem;                                // 16*1056*4 = 67584 B
    float*  epi = (float*)smem;                                // 8*2176*4 = 69632 B
    float4* pw_lds = (float4*)(smem + 69632);                  // 9216 B
    int4*   pi_lds = (int4*)(smem + 69632 + 9216);             // 9216 B

    int blk = blockIdx.x;
    int lb = (blk & 7) * 32 + (blk >> 3);        // XCD-slab swizzle
    int b = lb >> 6, h = lb & 63;
    int t = threadIdx.x;
    int wv = t >> 6, lane = t & 63;
    int ln = lane & 15, lq = lane >> 4;

    const unsigned short* xtb = xT + (size_t)b * (64 * 64 * 256);

    // ================= offsets prologue =================
    {
        int kq = wv >> 1, mh = wv & 1;
        f32x4 oacc[2][2];
#pragma unroll
        for (int m16 = 0; m16 < 2; ++m16)
#pragma unroll
            for (int nt = 0; nt < 2; ++nt)
                oacc[m16][nt] = (f32x4){0.f, 0.f, 0.f, 0.f};
        for (int u = kq * 9; u < kq * 9 + 9; ++u) {
            int tap = u >> 3, kc = u & 7;
            int ki = tap / 3, kj = tap - ki * 3;
            int hr = h + ki - 1;
            bf16x8 b0 = *(const bf16x8*)&Bo[(tap * 8 + kc) * 1024 + lq * 256 + ln * 8];
            bf16x8 b1 = *(const bf16x8*)&Bo[(tap * 8 + kc) * 1024 + lq * 256 + (16 + ln) * 8];
#pragma unroll
            for (int m16 = 0; m16 < 2; ++m16) {
                int wr = mh * 32 + m16 * 16 + ln + kj - 1;
                bf16x8 af = (bf16x8)(__bf16)0.0f;
                if (hr >= 0 && hr < 64 && wr >= 0 && wr < 64)
                    af = *(const bf16x8*)&yT[((size_t)(b * 64 + hr) * 64 + wr) * 256 + kc * 32 + lq * 8];
                oacc[m16][0] = __builtin_amdgcn_mfma_f32_16x16x32_bf16(af, b0, oacc[m16][0], 0, 0, 0);
                oacc[m16][1] = __builtin_amdgcn_mfma_f32_16x16x32_bf16(af, b1, oacc[m16][1], 0, 0, 0);
            }
        }
        float* rz = red + (size_t)(kq * 2 + mh) * 1056;
#pragma unroll
        for (int m16 = 0; m16 < 2; ++m16)
#pragma unroll
            for (int nt = 0; nt < 2; ++nt) {
                int o_l = nt * 16 + ln;
#pragma unroll
                for (int r = 0; r < 4; ++r)
                    rz[o_l * 33 + m16 * 16 + lq * 4 + r] = oacc[m16][nt][r];
            }
    }
    __syncthreads();
    // params: 576 jobs = (tap, pos)
    if (t < 576) {
        int tap = t >> 6, pos = t & 63;
        int mh_p = pos >> 5, pl = pos & 31;
        float dy = ob[2 * tap], dx = ob[2 * tap + 1];
#pragma unroll
        for (int kq = 0; kq < 8; ++kq) {
            const float* rz = red + (size_t)(kq * 2 + mh_p) * 1056;
            dy += rz[(2 * tap) * 33 + pl];
            dx += rz[(2 * tap + 1) * 33 + pl];
        }
        int ki = tap / 3, kj = tap - ki * 3;
        float py = (float)(h - 1 + ki) + dy;
        float px = (float)(pos - 1 + kj) + dx;
        float y0 = floorf(py), x0 = floorf(px);
        float wy1 = py - y0, wx1 = px - x0;
        float wy0 = 1.f - wy1, wx0 = 1.f - wx1;
        float y1 = y0 + 1.f, x1 = x0 + 1.f;
        float vy0 = (y0 >= 0.f && y0 <= 63.f) ? 1.f : 0.f;
        float vy1 = (y1 >= 0.f && y1 <= 63.f) ? 1.f : 0.f;
        float vx0 = (x0 >= 0.f && x0 <= 63.f) ? 1.f : 0.f;
        float vx1 = (x1 >= 0.f && x1 <= 63.f) ? 1.f : 0.f;
        int iy0 = (int)fminf(fmaxf(y0, 0.f), 63.f);
        int iy1 = (int)fminf(fmaxf(y1, 0.f), 63.f);
        int ix0 = (int)fminf(fmaxf(x0, 0.f), 63.f);
        int ix1 = (int)fminf(fmaxf(x1, 0.f), 63.f);
        pw_lds[t] = make_float4(wy0 * wx0 * vy0 * vx0, wy0 * wx1 * vy0 * vx1,
                                wy1 * wx0 * vy1 * vx0, wy1 * wx1 * vy1 * vx1);
        pi_lds[t] = make_int4((iy0 * 64 + ix0) * 256, (iy0 * 64 + ix1) * 256,
                              (iy1 * 64 + ix0) * 256, (iy1 * 64 + ix1) * 256);
    }
    __syncthreads();

    // ================= main implicit GEMM =================
    int ns = wv & 7, kh = wv >> 3;

    f32x4 acc[4][2];
#pragma unroll
    for (int ms = 0; ms < 4; ++ms)
#pragma unroll
        for (int nt = 0; nt < 2; ++nt)
            acc[ms][nt] = (f32x4){0.f, 0.f, 0.f, 0.f};

    int gr = t & 31, c0 = gr * 8;
    uint4 ga[2][4]; float4 gw[2];
    // gather tap 0
#pragma unroll
    for (int it = 0; it < 2; ++it) {
        int pos = (t >> 5) + it * 32;
        gw[it] = pw_lds[pos];
        int4 p = pi_lds[pos];
        ga[it][0] = *(const uint4*)&xtb[p.x + c0];
        ga[it][1] = *(const uint4*)&xtb[p.y + c0];
        ga[it][2] = *(const uint4*)&xtb[p.z + c0];
        ga[it][3] = *(const uint4*)&xtb[p.w + c0];
    }
#pragma unroll
    for (int it = 0; it < 2; ++it) {
        int pos = (t >> 5) + it * 32;
        uint4 res;
        res.x = blend2(ga[it][0].x, ga[it][1].x, ga[it][2].x, ga[it][3].x, gw[it]);
        res.y = blend2(ga[it][0].y, ga[it][1].y, ga[it][2].y, ga[it][3].y, gw[it]);
        res.z = blend2(ga[it][0].z, ga[it][1].z, ga[it][2].z, ga[it][3].z, gw[it]);
        res.w = blend2(ga[it][0].w, ga[it][1].w, ga[it][2].w, ga[it][3].w, gw[it]);
        *(uint4*)&Abuf0[pos * 256 + (gr ^ (pos & 7)) * 8] = res;
    }
    __syncthreads();

    for (int tap = 0; tap < 9; ++tap) {
        // issue next tap's gather loads
        if (tap < 8) {
#pragma unroll
            for (int it = 0; it < 2; ++it) {
                int pos = (t >> 5) + it * 32;
                gw[it] = pw_lds[(tap + 1) * 64 + pos];
                int4 p = pi_lds[(tap + 1) * 64 + pos];
                ga[it][0] = *(const uint4*)&xtb[p.x + c0];
                ga[it][1] = *(const uint4*)&xtb[p.y + c0];
                ga[it][2] = *(const uint4*)&xtb[p.z + c0];
                ga[it][3] = *(const uint4*)&xtb[p.w + c0];
            }
        }
        // MFMA on current tap
        const unsigned short* Ab = (tap & 1) ? Abuf1 : Abuf0;
#pragma unroll
        for (int kc = 0; kc < 4; ++kc) {
            int gbase = kh * 16 + kc * 4 + lq;
            bf16x8 af[4];
#pragma unroll
            for (int ms = 0; ms < 4; ++ms) {
                int row = ms * 16 + ln;
                af[ms] = *(const bf16x8*)&Ab[row * 256 + (gbase ^ (row & 7)) * 8];
            }
            int kg = tap * 8 + kh * 4 + kc;
            bf16x8 bfr[2];
#pragma unroll
            for (int nt = 0; nt < 2; ++nt)
                bfr[nt] = *(const bf16x8*)&Wp2[((kg * 4 + lq) * 256 + ns * 32 + nt * 16 + ln) * 8];
#pragma unroll
            for (int ms = 0; ms < 4; ++ms)
#pragma unroll
                for (int nt = 0; nt < 2; ++nt)
                    acc[ms][nt] = __builtin_amdgcn_mfma_f32_16x16x32_bf16(af[ms], bfr[nt], acc[ms][nt], 0, 0, 0);
        }
        // commit next tap
        if (tap < 8) {
            unsigned short* buf = (tap & 1) ? Abuf0 : Abuf1;
#pragma unroll
            for (int it = 0; it < 2; ++it) {
                int pos = (t >> 5) + it * 32;
                uint4 res;
                res.x = blend2(ga[it][0].x, ga[it][1].x, ga[it][2].x, ga[it][3].x, gw[it]);
                res.y = blend2(ga[it][0].y, ga[it][1].y, ga[it][2].y, ga[it][3].y, gw[it]);
                res.z = blend2(ga[it][0].z, ga[it][1].z, ga[it][2].z, ga[it][3].z, gw[it]);
                res.w = blend2(ga[it][0].w, ga[it][1].w, ga[it][2].w, ga[it][3].w, gw[it]);
                *(uint4*)&buf[pos * 256 + (gr ^ (pos & 7)) * 8] = res;
            }
        }
        __syncthreads();
    }

    // ================= epilogue =================
    if (kh == 1) {
        float* e = epi + (size_t)ns * 2176;
#pragma unroll
        for (int ms = 0; ms < 4; ++ms)
#pragma unroll
            for (int nt = 0; nt < 2; ++nt) {
                int o_l = nt * 16 + ln;
                f32x4 a = acc[ms][nt];
                *(float4*)&e[o_l * 68 + ms * 16 + lq * 4] = make_float4(a[0], a[1], a[2], a[3]);
            }
    }
    __syncthreads();
    if (kh == 0) {
        const float* e = epi + (size_t)ns * 2176;
#pragma unroll
        for (int ms = 0; ms < 4; ++ms)
#pragma unroll
            for (int nt = 0; nt < 2; ++nt) {
                int o_l = nt * 16 + ln;
                int o = ns * 32 + o_l;
                float bias = db[o];
                float4 p = *(const float4*)&e[o_l * 68 + ms * 16 + lq * 4];
                f32x4 a = acc[ms][nt];
                float4 st = make_float4(a[0] + p.x + bias, a[1] + p.y + bias,
                                        a[2] + p.z + bias, a[3] + p.w + bias);
                *(float4*)&out[((size_t)(b * 256 + o)) * 4096 + h * 64 + ms * 16 + lq * 4] = st;
            }
    }
}

extern "C" void kernel_launch(void* const* d_in, const int* in_sizes, int n_in,
                              void* d_out, int out_size, void* d_ws, size_t ws_size,
                              hipStream_t stream) {
    const float* x  = (const float*)d_in[0];
    const float* y  = (const float*)d_in[1];
    const float* ow = (const float*)d_in[2];
    const float* ob = (const float*)d_in[3];
    const float* dw = (const float*)d_in[4];
    const float* db = (const float*)d_in[5];
    float* out = (float*)d_out;

    char* ws = (char*)d_ws;
    unsigned short* xT  = (unsigned short*)(ws);
    unsigned short* yT  = (unsigned short*)(ws + 8388608);
    unsigned short* Wp2 = (unsigned short*)(ws + 16777216);
    unsigned short* Bo  = (unsigned short*)(ws + 16777216 + 1179648);

    hipLaunchKernelGGL(prep_kernel, dim3(2624), dim3(256), 0, stream,
                       x, y, ow, dw, xT, yT, Wp2, Bo);
    hipLaunchKernelGGL(deform_kernel, dim3(256), dim3(1024), 0, stream,
                       xT, yT, Wp2, Bo, ob, db, out);
}